// Round 5
// baseline (346.242 us; speedup 1.0000x reference)
//
#include <hip/hip_runtime.h>
#include <hip/hip_bf16.h>

#define HEADS 8
#define D 128
// log2(e) / sqrt(128): q is pre-scaled by this so scores are in exp2 domain.
#define QSCALE 0.12751743f

typedef unsigned short u16;
typedef unsigned int u32;
typedef __attribute__((ext_vector_type(8))) short short8;
typedef __attribute__((ext_vector_type(4))) float f32x4;

static __device__ inline float sbf2f(short s) {
    return __uint_as_float(((u32)(unsigned short)s) << 16);
}
static __device__ inline u16 f2bf(float f) {
    u32 u = __float_as_uint(f);
    return (u16)((u + 0x7FFFu + ((u >> 16) & 1u)) >> 16);
}
static __device__ inline u32 pk2bf(float a, float b) {
    return (u32)f2bf(a) | ((u32)f2bf(b) << 16);
}
static __device__ inline f32x4 mfma16(short8 a, short8 b, f32x4 c) {
    return __builtin_amdgcn_mfma_f32_16x16x32_bf16(a, b, c, 0, 0, 0);
}

// ---------------- K0: convert Wq,Wk,Wv to bf16 ----------------
__global__ __launch_bounds__(256) void k_wcvt(const float* __restrict__ Wq,
    const float* __restrict__ Wk, const float* __restrict__ Wv,
    u16* __restrict__ wqk, u16* __restrict__ wv)
{
    int idx = (blockIdx.x * 256 + threadIdx.x) * 4;   // 393216 floats total
    const float* src;
    u16* dst;
    if (idx < 131072)      { src = Wq + idx;           dst = wqk + idx; }
    else if (idx < 262144) { src = Wk + (idx - 131072); dst = wqk + idx; }
    else                   { src = Wv + (idx - 262144); dst = wv + (idx - 262144); }
    f32x4 v = *(const f32x4*)src;
    u32 p0 = pk2bf(v[0], v[1]);
    u32 p1 = pk2bf(v[2], v[3]);
    *(uint2*)dst = make_uint2(p0, p1);
}

// ---------------- K1: LayerNorm (f32 + bf16 outputs) ----------------
__global__ __launch_bounds__(256) void k_ln(const float* __restrict__ hs,
    const float* __restrict__ g, const float* __restrict__ b,
    float* __restrict__ xf, u16* __restrict__ xbf)
{
    int row  = blockIdx.x * 4 + (threadIdx.x >> 6);
    int lane = threadIdx.x & 63;
    const float* p = hs + (size_t)row * D + lane * 2;
    float2 v = *(const float2*)p;
    float s  = v.x + v.y;
    float s2 = v.x * v.x + v.y * v.y;
    #pragma unroll
    for (int off = 1; off < 64; off <<= 1) {
        s  += __shfl_xor(s, off);
        s2 += __shfl_xor(s2, off);
    }
    float mu  = s * 0.0078125f;
    float var = s2 * 0.0078125f - mu * mu;
    float inv = rsqrtf(var + 1e-5f);
    float2 o;
    o.x = (v.x - mu) * inv * g[lane * 2 + 0] + b[lane * 2 + 0];
    o.y = (v.y - mu) * inv * g[lane * 2 + 1] + b[lane * 2 + 1];
    *(float2*)(xf + (size_t)row * D + lane * 2) = o;
    *(u32*)(xbf + (size_t)row * D + lane * 2) = pk2bf(o.x, o.y);
}

// ---------------- K1b: transpose x -> xt[b][d][pos] bf16 ----------------
__global__ __launch_bounds__(256) void k_xt(const float* __restrict__ xf,
    u16* __restrict__ xt)
{
    __shared__ __align__(16) u16 tl[128][136];
    int b = blockIdx.x, ch = blockIdx.y;
    int tid = threadIdx.x;
    const float* src = xf + ((size_t)b * 1024 + ch * 128) * 128;
    #pragma unroll
    for (int it = 0; it < 16; ++it) {
        int s = tid + it * 256;
        int p = s >> 5, d4 = (s & 31) * 4;
        f32x4 v = *(const f32x4*)(src + (size_t)p * 128 + d4);
        tl[d4 + 0][p] = f2bf(v[0]);
        tl[d4 + 1][p] = f2bf(v[1]);
        tl[d4 + 2][p] = f2bf(v[2]);
        tl[d4 + 3][p] = f2bf(v[3]);
    }
    __syncthreads();
    u16* dst = xt + (size_t)b * 131072 + ch * 128;
    #pragma unroll
    for (int i = 0; i < 8; ++i) {
        int d = (tid >> 4) + i * 16, c8 = (tid & 15) * 8;
        *(uint4*)(dst + (size_t)d * 1024 + c8) = *(const uint4*)&tl[d][c8];
    }
}

// ---------------- K2: Q/K projection (MFMA bf16, bf16 weights) ----------------
// Q outputs are pre-scaled by QSCALE (content, row-bias, col-bias all inherit it).
__global__ __launch_bounds__(256) void k_proj(const u16* __restrict__ xbf,
    const u16* __restrict__ wqk,
    u16* __restrict__ q_bf, u16* __restrict__ kt_bf)
{
    int tid = threadIdx.x;
    int w = tid >> 6, l = tid & 63, h = l >> 4, ln = l & 15;
    int t0 = blockIdx.x * 64 + w * 16;
    int o0 = blockIdx.y * 64;
    short8 a[4];
    #pragma unroll
    for (int s = 0; s < 4; ++s)
        a[s] = *(const short8*)(xbf + (size_t)(t0 + ln) * 128 + s * 32 + h * 8);
    f32x4 acc[4];
    #pragma unroll
    for (int n = 0; n < 4; ++n) acc[n] = f32x4{0.f, 0.f, 0.f, 0.f};
    #pragma unroll
    for (int n = 0; n < 4; ++n) {
        const u16* wsrc = wqk + (size_t)(o0 + n * 16 + ln) * 128;
        #pragma unroll
        for (int s = 0; s < 4; ++s) {
            short8 bf = *(const short8*)(wsrc + s * 32 + h * 8);
            acc[n] = mfma16(a[s], bf, acc[n]);
        }
    }
    bool isq = (o0 < 1024);
    float oscale = isq ? QSCALE : 1.0f;
    int head = (o0 & 1023) >> 7;
    int od_base = (o0 & 127);
    u16* basep = isq ? q_bf : kt_bf;
    #pragma unroll
    for (int n = 0; n < 4; ++n) {
        int d0 = od_base + n * 16 + ln;
        #pragma unroll
        for (int r = 0; r < 4; ++r) {
            int t = t0 + h * 4 + r;
            int b = t >> 10, pos = t & 1023;
            size_t row;
            if (isq) row = (size_t)(b * 8 + head) * 1024 + pos;
            else { int I = pos >> 5, J = pos & 31; row = (size_t)(b * 8 + head) * 1024 + (J * 32 + I); }
            basep[row * 128 + d0] = f2bf(acc[n][r] * oscale);
        }
    }
}

// ---------------- K4: fused bias-GEMM + scores + softmax + PV ----------------
// block (bx, bh): bx -> I = bx>>1, Jbase = (bx&1)*16. 16 q-rows per block.
// 4 waves, each owning a 256-kk span. S^T layout: acc[t] holds
// S[kk = kk0 + t*16 + h*4 + r][J = Jbase + ln], all in exp2 domain (q pre-scaled).
__global__ __launch_bounds__(256, 2) void k_attn(const u16* __restrict__ q_bf,
    const u16* __restrict__ kt_bf, const u16* __restrict__ xt_bf,
    const float* __restrict__ row_emb, const float* __restrict__ col_emb,
    float* __restrict__ probs, u16* __restrict__ ctx_bf)
{
    __shared__ __align__(16) char Praw[32768];           // P (bf16, swizzled); aliased by re/ce staging
    __shared__ __align__(16) float rb_s[16 * 36];        // rb[j][K], pitch 36
    __shared__ __align__(16) float cb_s[16 * 64];        // Ccb[j][p], pitch 64
    __shared__ float wred[2][64];                        // [max|sum][w*16+j]
    char* P = Praw;
    u16* re_bf = (u16*)Praw;            // [32][64]  (4 KB)
    u16* ce_bf = (u16*)(Praw + 4096);   // [64][64]  (8 KB)

    int tid = threadIdx.x;
    int w = tid >> 6, l = tid & 63, h = l >> 4, ln = l & 15;
    int bx = blockIdx.x, bh = blockIdx.y;
    int b = bh >> 3, head = bh & 7;
    int I = bx >> 1;
    int Jbase = (bx & 1) * 16;

    // ---- stage re' (row_emb gathered at I) and ce (col_emb) as bf16 ----
    {
        int K = tid >> 3, d8 = (tid & 7) * 8;
        const float* src = row_emb + (size_t)(K - I + 31) * 64 + d8;
        f32x4 v0 = *(const f32x4*)src;
        f32x4 v1 = *(const f32x4*)(src + 4);
        *(uint4*)(re_bf + K * 64 + d8) = make_uint4(
            pk2bf(v0[0], v0[1]), pk2bf(v0[2], v0[3]),
            pk2bf(v1[0], v1[1]), pk2bf(v1[2], v1[3]));
    }
    #pragma unroll
    for (int it = 0; it < 2; ++it) {
        int s = tid + it * 256;
        int p = s >> 3, d8 = (s & 7) * 8;
        uint4 o;
        if (p < 63) {
            const float* src = col_emb + (size_t)p * 64 + d8;
            f32x4 v0 = *(const f32x4*)src;
            f32x4 v1 = *(const f32x4*)(src + 4);
            o = make_uint4(pk2bf(v0[0], v0[1]), pk2bf(v0[2], v0[3]),
                           pk2bf(v1[0], v1[1]), pk2bf(v1[2], v1[3]));
        } else o = make_uint4(0, 0, 0, 0);
        *(uint4*)(ce_bf + p * 64 + d8) = o;
    }

    // ---- Q fragments (A-op for bias GEMMs, B-op for QK^T) ----
    short8 qa[4];
    const u16* qbase = q_bf + ((size_t)bh * 1024 + I * 32 + Jbase) * 128;
    #pragma unroll
    for (int s = 0; s < 4; ++s)
        qa[s] = *(const short8*)(qbase + (size_t)ln * 128 + s * 32 + h * 8);

    __syncthreads();   // staging complete

    // ---- bias GEMMs: w0 -> rb[16x32]; w1,w2 -> cb[16x32 each]; w3 idle ----
    if (w == 0) {
        f32x4 arb[2] = {f32x4{0,0,0,0}, f32x4{0,0,0,0}};
        #pragma unroll
        for (int s = 0; s < 2; ++s)
            #pragma unroll
            for (int nt = 0; nt < 2; ++nt) {
                short8 bf = *(const short8*)(re_bf + (nt * 16 + ln) * 64 + s * 32 + h * 8);
                arb[nt] = mfma16(qa[s], bf, arb[nt]);
            }
        #pragma unroll
        for (int nt = 0; nt < 2; ++nt)
            #pragma unroll
            for (int r = 0; r < 4; ++r)
                rb_s[(h * 4 + r) * 36 + nt * 16 + ln] = arb[nt][r];
    } else if (w <= 2) {
        int pb = (w - 1) * 32;
        f32x4 acb[2] = {f32x4{0,0,0,0}, f32x4{0,0,0,0}};
        #pragma unroll
        for (int s = 0; s < 2; ++s)
            #pragma unroll
            for (int nt = 0; nt < 2; ++nt) {
                short8 bf = *(const short8*)(ce_bf + (pb + nt * 16 + ln) * 64 + s * 32 + h * 8);
                acb[nt] = mfma16(qa[2 + s], bf, acb[nt]);
            }
        #pragma unroll
        for (int nt = 0; nt < 2; ++nt)
            #pragma unroll
            for (int r = 0; r < 4; ++r)
                cb_s[(h * 4 + r) * 64 + pb + nt * 16 + ln] = acb[nt][r];
    }

    // ---- phase 1: S^T = K Q^T over this wave's 256-kk span ----
    // FULL unroll mandatory: partial unroll -> runtime-indexed acc -> scratch (rule #20).
    f32x4 acc[16];
    #pragma unroll
    for (int t = 0; t < 16; ++t) acc[t] = f32x4{0.f, 0.f, 0.f, 0.f};
    int kk0 = w * 256;
    const u16* kbase = kt_bf + ((size_t)bh * 1024 + kk0) * 128;
    #pragma unroll
    for (int t = 0; t < 16; ++t) {
        #pragma unroll
        for (int s = 0; s < 4; ++s) {
            short8 kf = *(const short8*)(kbase + (size_t)(t * 16 + ln) * 128 + s * 32 + h * 8);
            acc[t] = mfma16(kf, qa[s], acc[t]);
        }
    }
    __syncthreads();   // rb_s / cb_s ready

    // ---- per-lane bias registers (this lane's column j = ln) ----
    f32x4 rbr[2];
    float cbr[8];
    #pragma unroll
    for (int par = 0; par < 2; ++par)
        rbr[par] = *(const f32x4*)&rb_s[ln * 36 + par * 16 + h * 4];
    #pragma unroll
    for (int lL = 0; lL < 8; ++lL) {
        int L = (kk0 >> 5) + lL;
        cbr[lL] = cb_s[ln * 64 + (L - (Jbase + ln) + 31)];
    }

    // ---- bias add + row max (already in exp2 domain; no scale mul) ----
    {
        float mx = -1e30f;
        #pragma unroll
        for (int t = 0; t < 16; ++t) {
            float cbv = cbr[t >> 1];
            #pragma unroll
            for (int r = 0; r < 4; ++r) {
                float v = acc[t][r] + rbr[t & 1][r] + cbv;
                acc[t][r] = v;
                mx = fmaxf(mx, v);
            }
        }
        mx = fmaxf(mx, __shfl_xor(mx, 16));
        mx = fmaxf(mx, __shfl_xor(mx, 32));
        if (l < 16) wred[0][w * 16 + ln] = mx;
    }
    __syncthreads();

    // ---- exp2 + sum + packed P~ store ----
    {
        float M = fmaxf(fmaxf(wred[0][ln], wred[0][16 + ln]),
                        fmaxf(wred[0][32 + ln], wred[0][48 + ln]));
        float sum = 0.f;
        #pragma unroll
        for (int t = 0; t < 16; ++t) {
            float p0 = exp2f(acc[t][0] - M);
            float p1 = exp2f(acc[t][1] - M);
            float p2 = exp2f(acc[t][2] - M);
            float p3 = exp2f(acc[t][3] - M);
            sum += (p0 + p1) + (p2 + p3);
            int kk = kk0 + t * 16 + h * 4;
            int byteoff = ln * 2048 + ((kk * 2) ^ ((ln & 7) << 4));
            *(uint2*)(P + byteoff) = make_uint2(pk2bf(p0, p1), pk2bf(p2, p3));
        }
        sum += __shfl_xor(sum, 16);
        sum += __shfl_xor(sum, 32);
        if (l < 16) wred[1][w * 16 + ln] = sum;
    }
    __syncthreads();

    // ---- phase 3: ctx = P~ @ X  (wave w -> d-span w*32) ----
    f32x4 cacc[2] = {f32x4{0,0,0,0}, f32x4{0,0,0,0}};
    int d0 = w * 32;
    const u16* xb = xt_bf + (size_t)b * 131072;
    #pragma unroll 4
    for (int ks = 0; ks < 32; ++ks) {
        int byteoff = ln * 2048 + (((ks * 32 + h * 8) * 2) ^ ((ln & 7) << 4));
        short8 pa = *(const short8*)(P + byteoff);
        #pragma unroll
        for (int nt = 0; nt < 2; ++nt) {
            short8 xf8 = *(const short8*)(xb + (size_t)(d0 + nt * 16 + ln) * 1024 + ks * 32 + h * 8);
            cacc[nt] = mfma16(pa, xf8, cacc[nt]);
        }
    }
    // ---- ctx epilogue ----
    #pragma unroll
    for (int r = 0; r < 4; ++r) {
        int j = h * 4 + r;
        int J = Jbase + j;
        float lsum = wred[1][j] + wred[1][16 + j] + wred[1][32 + j] + wred[1][48 + j];
        float inv = 1.0f / lsum;
        u16* dst = ctx_bf + ((size_t)(b * 32 + J) * 32 + I) * 1024 + head * 128 + d0;
        dst[ln]      = f2bf(cacc[0][r] * inv);
        dst[16 + ln] = f2bf(cacc[1][r] * inv);
    }
    // ---- probs drain (normalized f32, coalesced) ----
    {
        int j = tid >> 4;
        int J = Jbase + j;
        float lsum = wred[1][j] + wred[1][16 + j] + wred[1][32 + j] + wred[1][48 + j];
        float inv = 1.0f / lsum;
        float* prow = probs + ((((size_t)(b * 32 + J) * 32 + I) * 8 + head) << 10);
        #pragma unroll
        for (int i = 0; i < 8; ++i) {
            int kk = i * 128 + (tid & 15) * 8;
            int byteoff = j * 2048 + ((kk * 2) ^ ((j & 7) << 4));
            short8 pv = *(const short8*)(P + byteoff);
            float4 o0, o1;
            o0.x = sbf2f(pv[0]) * inv; o0.y = sbf2f(pv[1]) * inv;
            o0.z = sbf2f(pv[2]) * inv; o0.w = sbf2f(pv[3]) * inv;
            o1.x = sbf2f(pv[4]) * inv; o1.y = sbf2f(pv[5]) * inv;
            o1.z = sbf2f(pv[6]) * inv; o1.w = sbf2f(pv[7]) * inv;
            *(float4*)(prow + kk)     = o0;
            *(float4*)(prow + kk + 4) = o1;
        }
    }
}

// ---------------- K7: output = ctx @ Wv^T + bv + x (MFMA) ----------------
__global__ __launch_bounds__(256) void k_out(const u16* __restrict__ ctx_bf,
    const u16* __restrict__ wv_bf, const float* __restrict__ bv,
    const float* __restrict__ xf, float* __restrict__ out)
{
    int tid = threadIdx.x;
    int w = tid >> 6, l = tid & 63, h = l >> 4, ln = l & 15;
    int wm = w >> 1, wn = w & 1;
    int t0 = blockIdx.x * 32 + wm * 16;
    int o0 = blockIdx.y * 64 + wn * 32;
    f32x4 acc[2] = {f32x4{0,0,0,0}, f32x4{0,0,0,0}};
    for (int ks = 0; ks < 32; ++ks) {
        short8 a = *(const short8*)(ctx_bf + (size_t)(t0 + ln) * 1024 + ks * 32 + h * 8);
        #pragma unroll
        for (int nt = 0; nt < 2; ++nt) {
            short8 bb = *(const short8*)(wv_bf + (size_t)(o0 + nt * 16 + ln) * 1024 + ks * 32 + h * 8);
            acc[nt] = mfma16(a, bb, acc[nt]);
        }
    }
    #pragma unroll
    for (int nt = 0; nt < 2; ++nt) {
        int o = o0 + nt * 16 + ln;
        float bvv = bv[o];
        #pragma unroll
        for (int r = 0; r < 4; ++r) {
            int t = t0 + h * 4 + r;
            out[(size_t)t * 128 + o] = acc[nt][r] + bvv + xf[(size_t)t * 128 + o];
        }
    }
}

extern "C" void kernel_launch(void* const* d_in, const int* in_sizes, int n_in,
                              void* d_out, int out_size, void* d_ws, size_t ws_size,
                              hipStream_t stream) {
    (void)in_sizes; (void)n_in; (void)out_size; (void)ws_size;
    const float* hs      = (const float*)d_in[0];
    const float* row_emb = (const float*)d_in[1];
    const float* col_emb = (const float*)d_in[2];
    const float* Wq      = (const float*)d_in[3];
    const float* Wk      = (const float*)d_in[4];
    const float* Wv      = (const float*)d_in[5];
    const float* bv      = (const float*)d_in[6];
    const float* ln_g    = (const float*)d_in[7];
    const float* ln_b    = (const float*)d_in[8];

    float* out   = (float*)d_out;
    float* probs = out + 1048576;

    char* ws = (char*)d_ws;
    float* xf     = (float*)(ws);                      //  4 MB
    u16*   xbf    = (u16*)(ws + 4194304);              //  2 MB
    u16*   q_bf   = (u16*)(ws + 6291456);              // 16 MB
    u16*   kt_bf  = (u16*)(ws + 23068672);             // 16 MB
    u16*   xt     = (u16*)(ws + 39845888);             //  2 MB
    u16*   wqk_bf = (u16*)(ws + 41943040);             // 512 KB
    u16*   wv_bf  = (u16*)(ws + 42467328);             // 256 KB
    u16*   ctx    = (u16*)(ws + 42729472);             // 16 MB

    k_wcvt <<<384, 256, 0, stream>>>(Wq, Wk, Wv, wqk_bf, wv_bf);
    k_ln   <<<2048, 256, 0, stream>>>(hs, ln_g, ln_b, xf, xbf);
    k_xt   <<<dim3(8, 8), 256, 0, stream>>>(xf, xt);
    k_proj <<<dim3(128, 32), 256, 0, stream>>>(xbf, wqk_bf, q_bf, kt_bf);
    k_attn <<<dim3(64, 64), 256, 0, stream>>>(q_bf, kt_bf, xt, row_emb, col_emb, probs, ctx);
    k_out  <<<dim3(256, 2), 256, 0, stream>>>(ctx, wv_bf, bv, xf, out);
}

// Round 6
// 276.536 us; speedup vs baseline: 1.2521x; 1.2521x over previous
//
#include <hip/hip_runtime.h>
#include <hip/hip_bf16.h>

#define HEADS 8
#define D 128
// log2(e) / sqrt(128): q is pre-scaled by this so scores are in exp2 domain.
#define QSCALE 0.12751743f

typedef unsigned short u16;
typedef unsigned int u32;
typedef __attribute__((ext_vector_type(8))) short short8;
typedef __attribute__((ext_vector_type(4))) float f32x4;

static __device__ inline u16 f2bf(float f) {
    u32 u = __float_as_uint(f);
    return (u16)((u + 0x7FFFu + ((u >> 16) & 1u)) >> 16);
}
static __device__ inline u32 pk2bf(float a, float b) {
    return (u32)f2bf(a) | ((u32)f2bf(b) << 16);
}
static __device__ inline f32x4 mfma16(short8 a, short8 b, f32x4 c) {
    return __builtin_amdgcn_mfma_f32_16x16x32_bf16(a, b, c, 0, 0, 0);
}
// load 8 consecutive f32 and convert to a bf16 MFMA fragment
static __device__ inline short8 cvt8(const float* e) {
    f32x4 v0 = *(const f32x4*)e;
    f32x4 v1 = *(const f32x4*)(e + 4);
    union { uint4 u; short8 s; } x;
    x.u = make_uint4(pk2bf(v0[0], v0[1]), pk2bf(v0[2], v0[3]),
                     pk2bf(v1[0], v1[1]), pk2bf(v1[2], v1[3]));
    return x.s;
}

// ---------------- K0: convert Wq,Wk,Wv to bf16 ----------------
__global__ __launch_bounds__(256) void k_wcvt(const float* __restrict__ Wq,
    const float* __restrict__ Wk, const float* __restrict__ Wv,
    u16* __restrict__ wqk, u16* __restrict__ wv)
{
    int idx = (blockIdx.x * 256 + threadIdx.x) * 4;   // 393216 floats total
    const float* src;
    u16* dst;
    if (idx < 131072)      { src = Wq + idx;           dst = wqk + idx; }
    else if (idx < 262144) { src = Wk + (idx - 131072); dst = wqk + idx; }
    else                   { src = Wv + (idx - 262144); dst = wv + (idx - 262144); }
    f32x4 v = *(const f32x4*)src;
    *(uint2*)dst = make_uint2(pk2bf(v[0], v[1]), pk2bf(v[2], v[3]));
}

// ---------------- K1: LayerNorm (f32 + bf16 outputs) ----------------
__global__ __launch_bounds__(256) void k_ln(const float* __restrict__ hs,
    const float* __restrict__ g, const float* __restrict__ b,
    float* __restrict__ xf, u16* __restrict__ xbf)
{
    int row  = blockIdx.x * 4 + (threadIdx.x >> 6);
    int lane = threadIdx.x & 63;
    const float* p = hs + (size_t)row * D + lane * 2;
    float2 v = *(const float2*)p;
    float s  = v.x + v.y;
    float s2 = v.x * v.x + v.y * v.y;
    #pragma unroll
    for (int off = 1; off < 64; off <<= 1) {
        s  += __shfl_xor(s, off);
        s2 += __shfl_xor(s2, off);
    }
    float mu  = s * 0.0078125f;
    float var = s2 * 0.0078125f - mu * mu;
    float inv = rsqrtf(var + 1e-5f);
    float2 o;
    o.x = (v.x - mu) * inv * g[lane * 2 + 0] + b[lane * 2 + 0];
    o.y = (v.y - mu) * inv * g[lane * 2 + 1] + b[lane * 2 + 1];
    *(float2*)(xf + (size_t)row * D + lane * 2) = o;
    *(u32*)(xbf + (size_t)row * D + lane * 2) = pk2bf(o.x, o.y);
}

// ---------------- K1b: transpose x -> xt[b][d][pos] bf16 ----------------
__global__ __launch_bounds__(256) void k_xt(const float* __restrict__ xf,
    u16* __restrict__ xt)
{
    __shared__ __align__(16) u16 tl[128][136];
    int b = blockIdx.x, ch = blockIdx.y;
    int tid = threadIdx.x;
    const float* src = xf + ((size_t)b * 1024 + ch * 128) * 128;
    #pragma unroll
    for (int it = 0; it < 16; ++it) {
        int s = tid + it * 256;
        int p = s >> 5, d4 = (s & 31) * 4;
        f32x4 v = *(const f32x4*)(src + (size_t)p * 128 + d4);
        tl[d4 + 0][p] = f2bf(v[0]);
        tl[d4 + 1][p] = f2bf(v[1]);
        tl[d4 + 2][p] = f2bf(v[2]);
        tl[d4 + 3][p] = f2bf(v[3]);
    }
    __syncthreads();
    u16* dst = xt + (size_t)b * 131072 + ch * 128;
    #pragma unroll
    for (int i = 0; i < 8; ++i) {
        int d = (tid >> 4) + i * 16, c8 = (tid & 15) * 8;
        *(uint4*)(dst + (size_t)d * 1024 + c8) = *(const uint4*)&tl[d][c8];
    }
}

// ---------------- K2: Q/K projection (MFMA bf16, bf16 weights) ----------------
// Q outputs pre-scaled by QSCALE (content, row-bias, col-bias all inherit it).
__global__ __launch_bounds__(256) void k_proj(const u16* __restrict__ xbf,
    const u16* __restrict__ wqk,
    u16* __restrict__ q_bf, u16* __restrict__ kt_bf)
{
    int tid = threadIdx.x;
    int w = tid >> 6, l = tid & 63, h = l >> 4, ln = l & 15;
    int t0 = blockIdx.x * 64 + w * 16;
    int o0 = blockIdx.y * 64;
    short8 a[4];
    #pragma unroll
    for (int s = 0; s < 4; ++s)
        a[s] = *(const short8*)(xbf + (size_t)(t0 + ln) * 128 + s * 32 + h * 8);
    f32x4 acc[4];
    #pragma unroll
    for (int n = 0; n < 4; ++n) acc[n] = f32x4{0.f, 0.f, 0.f, 0.f};
    #pragma unroll
    for (int n = 0; n < 4; ++n) {
        const u16* wsrc = wqk + (size_t)(o0 + n * 16 + ln) * 128;
        #pragma unroll
        for (int s = 0; s < 4; ++s) {
            short8 bf = *(const short8*)(wsrc + s * 32 + h * 8);
            acc[n] = mfma16(a[s], bf, acc[n]);
        }
    }
    bool isq = (o0 < 1024);
    float oscale = isq ? QSCALE : 1.0f;
    int head = (o0 & 1023) >> 7;
    int od_base = (o0 & 127);
    u16* basep = isq ? q_bf : kt_bf;
    #pragma unroll
    for (int n = 0; n < 4; ++n) {
        int d0 = od_base + n * 16 + ln;
        #pragma unroll
        for (int r = 0; r < 4; ++r) {
            int t = t0 + h * 4 + r;
            int b = t >> 10, pos = t & 1023;
            size_t row;
            if (isq) row = (size_t)(b * 8 + head) * 1024 + pos;
            else { int I = pos >> 5, J = pos & 31; row = (size_t)(b * 8 + head) * 1024 + (J * 32 + I); }
            basep[row * 128 + d0] = f2bf(acc[n][r] * oscale);
        }
    }
}

// ---------------- K3: bias GEMMs -> rbias[J][K], cbias[J][L] (pre-gathered) ----
// block = (bh*32 + I).  rb[J][K] = q_row[J] . row_emb[K-I+31]
// cbias[J][L] = q_col[J] . col_emb[L-J+31]  (computed as full [J][p] GEMM + gather)
__global__ __launch_bounds__(256) void k_bias(const u16* __restrict__ q_bf,
    const float* __restrict__ row_emb, const float* __restrict__ col_emb,
    float* __restrict__ rbias, float* __restrict__ cbias)
{
    __shared__ __align__(16) float cbf[32][68];
    int tid = threadIdx.x;
    int w = tid >> 6, l = tid & 63, h = l >> 4, ln = l & 15;
    int blk = blockIdx.x;
    int bh = blk >> 5, I = blk & 31;
    const u16* qb = q_bf + ((size_t)bh * 1024 + I * 32) * 128;
    size_t obase = (size_t)blk * 1024;
    if (w < 2) {
        // rb m-tile w: A rows J = w*16+ln, d in [0,64)
        short8 a0 = *(const short8*)(qb + (size_t)(w * 16 + ln) * 128 + h * 8);
        short8 a1 = *(const short8*)(qb + (size_t)(w * 16 + ln) * 128 + 32 + h * 8);
        f32x4 o[2] = {f32x4{0,0,0,0}, f32x4{0,0,0,0}};
        #pragma unroll
        for (int n = 0; n < 2; ++n) {
            int K = n * 16 + ln;
            const float* e = row_emb + (size_t)(K - I + 31) * 64 + h * 8;
            o[n] = mfma16(a0, cvt8(e), o[n]);
            o[n] = mfma16(a1, cvt8(e + 32), o[n]);
        }
        #pragma unroll
        for (int n = 0; n < 2; ++n)
            #pragma unroll
            for (int r = 0; r < 4; ++r)
                rbias[obase + (size_t)(w * 16 + h * 4 + r) * 32 + n * 16 + ln] = o[n][r];
    } else {
        // cb full [J][p]: A rows J = (w-2)*16+ln, d in [64,128)
        int m = w - 2;
        short8 a0 = *(const short8*)(qb + (size_t)(m * 16 + ln) * 128 + 64 + h * 8);
        short8 a1 = *(const short8*)(qb + (size_t)(m * 16 + ln) * 128 + 96 + h * 8);
        f32x4 o[4] = {f32x4{0,0,0,0}, f32x4{0,0,0,0}, f32x4{0,0,0,0}, f32x4{0,0,0,0}};
        #pragma unroll
        for (int n = 0; n < 4; ++n) {
            int p = n * 16 + ln;
            if (p > 62) p = 62;            // clamp: p=63 never consumed
            const float* e = col_emb + (size_t)p * 64 + h * 8;
            o[n] = mfma16(a0, cvt8(e), o[n]);
            o[n] = mfma16(a1, cvt8(e + 32), o[n]);
        }
        #pragma unroll
        for (int n = 0; n < 4; ++n)
            #pragma unroll
            for (int r = 0; r < 4; ++r)
                cbf[m * 16 + h * 4 + r][n * 16 + ln] = o[n][r];
    }
    __syncthreads();
    // gather diagonal: cbias[J][L] = cbf[J][L - J + 31]
    int J = tid >> 3, L0 = (tid & 7) * 4;
    float4 g;
    g.x = cbf[J][L0 + 0 - J + 31];
    g.y = cbf[J][L0 + 1 - J + 31];
    g.z = cbf[J][L0 + 2 - J + 31];
    g.w = cbf[J][L0 + 3 - J + 31];
    *(float4*)(cbias + obase + (size_t)J * 32 + L0) = g;
}

// ---------------- K4: fused scores + softmax + PV ----------------
// 512 threads = 8 waves; block covers I (32 q-rows J), wave w owns kk-span w*128.
// S^T layout: acc[n][t] holds S[kk = w*128 + t*16 + h*4 + r][J = n*16 + ln],
// all in exp2 domain (q pre-scaled by QSCALE).
__global__ __launch_bounds__(512, 4) void k_attn(const u16* __restrict__ q_bf,
    const u16* __restrict__ kt_bf, const u16* __restrict__ xt_bf,
    const float* __restrict__ rbias, const float* __restrict__ cbias,
    float* __restrict__ probs, u16* __restrict__ ctx_bf)
{
    __shared__ __align__(16) char P[65536];       // P~ bf16, XOR-swizzled
    __shared__ float wred[2][256];                // [max|sum][w*32 + J]
    __shared__ float linv_s[32];                  // 1/sum per J

    int tid = threadIdx.x;
    int w = tid >> 6, l = tid & 63, h = l >> 4, ln = l & 15;
    // T1 XCD swizzle: 32 blocks sharing one bh land on one XCD (grid 2048 = 8*256)
    int flat = blockIdx.x;
    int swz = (flat & 7) * 256 + (flat >> 3);
    int bh = swz >> 5, I = swz & 31;
    int b = bh >> 3, head = bh & 7;
    int kk0 = w * 128;

    // ---- phase 1: S^T = K Q^T over this wave's 128-kk span ----
    // (s outer, qa loaded per-s: keeps peak VGPR pressure ~110 under the 128 cap)
    f32x4 acc[2][8];
    #pragma unroll
    for (int n = 0; n < 2; ++n)
        #pragma unroll
        for (int t = 0; t < 8; ++t) acc[n][t] = f32x4{0.f, 0.f, 0.f, 0.f};
    const u16* kbase = kt_bf + ((size_t)bh * 1024 + kk0) * 128;
    const u16* qbase = q_bf + ((size_t)bh * 1024 + I * 32) * 128;
    #pragma unroll
    for (int s = 0; s < 4; ++s) {
        short8 q0 = *(const short8*)(qbase + (size_t)ln * 128 + s * 32 + h * 8);
        short8 q1 = *(const short8*)(qbase + (size_t)(16 + ln) * 128 + s * 32 + h * 8);
        #pragma unroll
        for (int t = 0; t < 8; ++t) {
            short8 kf = *(const short8*)(kbase + (size_t)(t * 16 + ln) * 128 + s * 32 + h * 8);
            acc[0][t] = mfma16(kf, q0, acc[0][t]);
            acc[1][t] = mfma16(kf, q1, acc[1][t]);
        }
    }

    // ---- bias registers (precomputed by k_bias) ----
    const float* rbase = rbias + (size_t)(bh * 32 + I) * 1024;
    const float* cbase = cbias + (size_t)(bh * 32 + I) * 1024;
    f32x4 rbr[2][2], cbr[2];
    #pragma unroll
    for (int n = 0; n < 2; ++n) {
        int J = n * 16 + ln;
        rbr[n][0] = *(const f32x4*)(rbase + J * 32 + h * 4);
        rbr[n][1] = *(const f32x4*)(rbase + J * 32 + 16 + h * 4);
        cbr[n]    = *(const f32x4*)(cbase + J * 32 + w * 4);
    }

    // ---- bias add + row max ----
    #pragma unroll
    for (int n = 0; n < 2; ++n) {
        float mx = -1e30f;
        #pragma unroll
        for (int t = 0; t < 8; ++t) {
            float cbv = cbr[n][t >> 1];
            #pragma unroll
            for (int r = 0; r < 4; ++r) {
                float v = acc[n][t][r] + rbr[n][t & 1][r] + cbv;
                acc[n][t][r] = v;
                mx = fmaxf(mx, v);
            }
        }
        mx = fmaxf(mx, __shfl_xor(mx, 16));
        mx = fmaxf(mx, __shfl_xor(mx, 32));
        if (l < 16) wred[0][w * 32 + n * 16 + ln] = mx;
    }
    __syncthreads();

    // ---- exp2 + sum + packed P~ store ----
    #pragma unroll
    for (int n = 0; n < 2; ++n) {
        int J = n * 16 + ln;
        float M = wred[0][J];
        #pragma unroll
        for (int w2 = 1; w2 < 8; ++w2) M = fmaxf(M, wred[0][w2 * 32 + J]);
        float sum = 0.f;
        #pragma unroll
        for (int t = 0; t < 8; ++t) {
            float p0 = exp2f(acc[n][t][0] - M);
            float p1 = exp2f(acc[n][t][1] - M);
            float p2 = exp2f(acc[n][t][2] - M);
            float p3 = exp2f(acc[n][t][3] - M);
            acc[n][t] = f32x4{p0, p1, p2, p3};
            sum += (p0 + p1) + (p2 + p3);
            int kk = kk0 + t * 16 + h * 4;
            *(uint2*)(P + J * 2048 + ((kk * 2) ^ ((J & 7) << 4))) =
                make_uint2(pk2bf(p0, p1), pk2bf(p2, p3));
        }
        sum += __shfl_xor(sum, 16);
        sum += __shfl_xor(sum, 32);
        if (l < 16) wred[1][w * 32 + J] = sum;
    }
    __syncthreads();
    if (tid < 32) {
        float s = 0.f;
        #pragma unroll
        for (int w2 = 0; w2 < 8; ++w2) s += wred[1][w2 * 32 + tid];
        linv_s[tid] = 1.0f / s;
    }
    __syncthreads();

    // ---- probs drain straight from registers (f32, no LDS re-read) ----
    #pragma unroll
    for (int n = 0; n < 2; ++n) {
        int J = n * 16 + ln;
        float inv = linv_s[J];
        float* prow = probs + ((((size_t)(b * 32 + J) * 32 + I) * 8 + head) << 10)
                    + kk0 + h * 4;
        #pragma unroll
        for (int t = 0; t < 8; ++t) {
            *(float4*)(prow + t * 16) = make_float4(
                acc[n][t][0] * inv, acc[n][t][1] * inv,
                acc[n][t][2] * inv, acc[n][t][3] * inv);
        }
    }

    // ---- PV: ctx = P~ @ X  (wave w -> d-span w*16) ----
    f32x4 cacc[2] = {f32x4{0,0,0,0}, f32x4{0,0,0,0}};
    int d0 = w * 16;
    const u16* xb = xt_bf + (size_t)b * 131072 + (size_t)(d0 + ln) * 1024 + h * 8;
    #pragma unroll 4
    for (int ks = 0; ks < 32; ++ks) {
        short8 xf8 = *(const short8*)(xb + ks * 32);
        #pragma unroll
        for (int m = 0; m < 2; ++m) {
            int J = m * 16 + ln;
            short8 pa = *(const short8*)(P + J * 2048 +
                (((ks * 32 + h * 8) * 2) ^ ((J & 7) << 4)));
            cacc[m] = mfma16(pa, xf8, cacc[m]);
        }
    }
    #pragma unroll
    for (int m = 0; m < 2; ++m)
        #pragma unroll
        for (int r = 0; r < 4; ++r) {
            int J = m * 16 + h * 4 + r;
            ctx_bf[((size_t)(b * 32 + J) * 32 + I) * 1024 + head * 128 + d0 + ln] =
                f2bf(cacc[m][r] * linv_s[J]);
        }
}

// ---------------- K7: output = ctx @ Wv^T + bv + x (MFMA) ----------------
__global__ __launch_bounds__(256) void k_out(const u16* __restrict__ ctx_bf,
    const u16* __restrict__ wv_bf, const float* __restrict__ bv,
    const float* __restrict__ xf, float* __restrict__ out)
{
    int tid = threadIdx.x;
    int w = tid >> 6, l = tid & 63, h = l >> 4, ln = l & 15;
    int wm = w >> 1, wn = w & 1;
    int t0 = blockIdx.x * 32 + wm * 16;
    int o0 = blockIdx.y * 64 + wn * 32;
    f32x4 acc[2] = {f32x4{0,0,0,0}, f32x4{0,0,0,0}};
    for (int ks = 0; ks < 32; ++ks) {
        short8 a = *(const short8*)(ctx_bf + (size_t)(t0 + ln) * 1024 + ks * 32 + h * 8);
        #pragma unroll
        for (int nt = 0; nt < 2; ++nt) {
            short8 bb = *(const short8*)(wv_bf + (size_t)(o0 + nt * 16 + ln) * 1024 + ks * 32 + h * 8);
            acc[nt] = mfma16(a, bb, acc[nt]);
        }
    }
    #pragma unroll
    for (int nt = 0; nt < 2; ++nt) {
        int o = o0 + nt * 16 + ln;
        float bvv = bv[o];
        #pragma unroll
        for (int r = 0; r < 4; ++r) {
            int t = t0 + h * 4 + r;
            out[(size_t)t * 128 + o] = acc[nt][r] + bvv + xf[(size_t)t * 128 + o];
        }
    }
}

extern "C" void kernel_launch(void* const* d_in, const int* in_sizes, int n_in,
                              void* d_out, int out_size, void* d_ws, size_t ws_size,
                              hipStream_t stream) {
    (void)in_sizes; (void)n_in; (void)out_size; (void)ws_size;
    const float* hs      = (const float*)d_in[0];
    const float* row_emb = (const float*)d_in[1];
    const float* col_emb = (const float*)d_in[2];
    const float* Wq      = (const float*)d_in[3];
    const float* Wk      = (const float*)d_in[4];
    const float* Wv      = (const float*)d_in[5];
    const float* bv      = (const float*)d_in[6];
    const float* ln_g    = (const float*)d_in[7];
    const float* ln_b    = (const float*)d_in[8];

    float* out   = (float*)d_out;
    float* probs = out + 1048576;

    char* ws = (char*)d_ws;
    float* xf     = (float*)(ws);                      //  4 MB
    u16*   xbf    = (u16*)(ws + 4194304);              //  2 MB
    u16*   q_bf   = (u16*)(ws + 6291456);              // 16 MB
    u16*   kt_bf  = (u16*)(ws + 23068672);             // 16 MB
    u16*   xt     = (u16*)(ws + 39845888);             //  2 MB
    u16*   wqk_bf = (u16*)(ws + 41943040);             // 512 KB
    u16*   wv_bf  = (u16*)(ws + 42467328);             // 256 KB
    u16*   ctx    = (u16*)(ws + 42729472);             // 16 MB
    float* rbias  = (float*)(ws + 59506688);           //  8 MB
    float* cbias  = (float*)(ws + 67895296);           //  8 MB  (total 72.75 MB)

    k_wcvt <<<384, 256, 0, stream>>>(Wq, Wk, Wv, wqk_bf, wv_bf);
    k_ln   <<<2048, 256, 0, stream>>>(hs, ln_g, ln_b, xf, xbf);
    k_xt   <<<dim3(8, 8), 256, 0, stream>>>(xf, xt);
    k_proj <<<dim3(128, 32), 256, 0, stream>>>(xbf, wqk_bf, q_bf, kt_bf);
    k_bias <<<2048, 256, 0, stream>>>(q_bf, row_emb, col_emb, rbias, cbias);
    k_attn <<<2048, 512, 0, stream>>>(q_bf, kt_bf, xt, rbias, cbias, probs, ctx);
    k_out  <<<dim3(256, 2), 256, 0, stream>>>(ctx, wv_bf, bv, xf, out);
}